// Round 13
// baseline (249.381 us; speedup 1.0000x reference)
//
#include <hip/hip_runtime.h>
#include <hip/hip_bf16.h>

#define N_ATOMS 20000
#define N_BONDS 200000
#define MAX_DEG 12
#define IN_DIM 256
#define BOND_DIM 128
#define OUT_DIM 512
#define N_HEADS 8
#define HEAD_DIM 64

typedef __attribute__((ext_vector_type(8))) short short8v;
typedef __attribute__((ext_vector_type(4))) float f32x4;

static __device__ __forceinline__ float bf2f(unsigned int u) {
    union { unsigned int i; float f; } c;
    c.i = (u & 0xffffu) << 16;
    return c.f;
}
static __device__ __forceinline__ unsigned short f2bf(float f) {
    union { float f; unsigned int i; } c;
    c.f = f;
    unsigned int x = c.i;
    x += 0x7fffu + ((x >> 16) & 1u);   // round-to-nearest-even
    return (unsigned short)(x >> 16);
}

// ---------------------------------------------------------------------------
// PREP (fused): WtA (blocks 0..511), WtB (512..767), u_edge/c_edge (768..771)
// ---------------------------------------------------------------------------
__global__ __launch_bounds__(256) void prep_kernel(
    const float* __restrict__ W_atom, const float* __restrict__ W_bond,
    const float* __restrict__ att_edge, const float* __restrict__ b_bond,
    unsigned short* __restrict__ WtA, unsigned short* __restrict__ WtB,
    float* __restrict__ u_edge, float* __restrict__ c_edge) {
    const int b = blockIdx.x;
    if (b < 512) {                      // WtA[n][k] = bf16(W_atom[k][n]), K=256
        int id = b * 256 + threadIdx.x;
        int n = id >> 8, k = id & 255;
        WtA[id] = f2bf(W_atom[(size_t)k * 512 + n]);
    } else if (b < 768) {               // WtB[n][k] = bf16(W_bond[k][n]), K=128
        int id = (b - 512) * 256 + threadIdx.x;
        int n = id >> 7, k = id & 127;
        WtB[id] = f2bf(W_bond[(size_t)k * 512 + n]);
    } else {                            // u_edge / c_edge
        int tid = (b - 768) * 256 + threadIdx.x;
        if (tid >= 1024) return;
        int h = tid >> 7, c = tid & 127;
        const float* wrow = W_bond + (size_t)c * 512 + h * 64;
        const float* ae = att_edge + h * 64;
        float s = 0.f;
        #pragma unroll 8
        for (int k = 0; k < 64; ++k) s += wrow[k] * ae[k];
        u_edge[h * 128 + c] = s;
        if (c == 0) {
            float cs = 0.f;
            const float* bb = b_bond + h * 64;
            for (int k = 0; k < 64; ++k) cs += bb[k] * ae[k];
            c_edge[h] = cs;
        }
    }
}

// ---------------------------------------------------------------------------
// STAGE1 (fused): blocks 0..2503 = atom GEMM (round-4 proven, XCD swizzle);
// blocks 2504..8753 = escore. Union LDS (21152 B).
// ---------------------------------------------------------------------------
__global__ __launch_bounds__(256) void stage1_kernel(
    const float* __restrict__ x, const unsigned short* __restrict__ WtA,
    const float* __restrict__ b_atom, unsigned short* __restrict__ hA,
    const float* __restrict__ edge, const float* __restrict__ u_edge,
    const float* __restrict__ c_edge, float* __restrict__ score_edge) {
    __shared__ __align__(16) unsigned char smem[21152];
    const int t = threadIdx.x;

    if (blockIdx.x < 2504) {
        // ================= ATOM GEMM path (M=20000, K=256, nbm=313) ========
        unsigned short* Als = (unsigned short*)smem;
        unsigned short* Bls = (unsigned short*)(smem + 8192);
        const int wgid = (blockIdx.x & 7) * 313 + (blockIdx.x >> 3);
        const int bn = wgid & 7;
        const int bm = wgid >> 3;
        const int w = t >> 6;
        const int l = t & 63;

        f32x4 acc[4] = {};

        for (int kk = 0; kk < 4; ++kk) {
            #pragma unroll
            for (int i = 0; i < 2; ++i) {
                int c = t + i * 256;
                int row = c >> 3;
                int k8 = (c & 7) << 3;
                int grow = (bm << 6) + row;
                float f[8];
                if (grow < N_ATOMS) {
                    const float* src = x + (size_t)grow * 256 + (kk << 6) + k8;
                    float4 v0 = *(const float4*)src;
                    float4 v1 = *(const float4*)(src + 4);
                    f[0] = v0.x; f[1] = v0.y; f[2] = v0.z; f[3] = v0.w;
                    f[4] = v1.x; f[5] = v1.y; f[6] = v1.z; f[7] = v1.w;
                } else {
                    #pragma unroll
                    for (int j = 0; j < 8; ++j) f[j] = 0.f;
                }
                union { unsigned short us[8]; uint4 v; } pk;
                #pragma unroll
                for (int j = 0; j < 8; ++j) pk.us[j] = f2bf(f[j]);
                int byte = ((row << 7) + (k8 << 1)) ^ ((row & 7) << 4);
                *(uint4*)((char*)Als + byte) = pk.v;
            }
            #pragma unroll
            for (int i = 0; i < 2; ++i) {
                int c = t + i * 256;
                int row = c >> 3;
                int k8 = (c & 7) << 3;
                int gn = (bn << 6) + row;
                uint4 v = *(const uint4*)(WtA + (size_t)gn * 256 + (kk << 6) + k8);
                int byte = ((row << 7) + (k8 << 1)) ^ ((row & 7) << 4);
                *(uint4*)((char*)Bls + byte) = v;
            }
            __syncthreads();

            const int m = l & 15;
            const int kg = (l >> 4) << 3;
            #pragma unroll
            for (int ks = 0; ks < 2; ++ks) {
                int kcol = (ks << 5) + kg;
                int arow = (w << 4) + m;
                short8v a = *(short8v*)((char*)Als +
                    (((arow << 7) + (kcol << 1)) ^ ((arow & 7) << 4)));
                #pragma unroll
                for (int nt = 0; nt < 4; ++nt) {
                    int nrow = (nt << 4) + m;
                    short8v bfr = *(short8v*)((char*)Bls +
                        (((nrow << 7) + (kcol << 1)) ^ ((nrow & 7) << 4)));
                    acc[nt] = __builtin_amdgcn_mfma_f32_16x16x32_bf16(a, bfr, acc[nt], 0, 0, 0);
                }
            }
            __syncthreads();
        }

        const int m = l & 15;
        const int rbase = (bm << 6) + (w << 4) + ((l >> 4) << 2);
        #pragma unroll
        for (int nt = 0; nt < 4; ++nt) {
            int col = (bn << 6) + (nt << 4) + m;
            float bv = b_atom[col];
            #pragma unroll
            for (int r = 0; r < 4; ++r) {
                int grow = rbase + r;
                if (grow < N_ATOMS) hA[(size_t)grow * 512 + col] = f2bf(acc[nt][r] + bv);
            }
        }
    } else {
        // ================= ESCORE path: 32 bonds/block =====================
        float* eL = (float*)smem;                 // 32*132 floats
        float* uL = (float*)(smem + 16896);       // 8*132 floats
        float* cL = (float*)(smem + 21120);       // 8 floats
        const size_t b0 = (size_t)(blockIdx.x - 2504) * 32;
        #pragma unroll
        for (int i = 0; i < 4; ++i) {
            int idx = i * 256 + t;
            int row = idx >> 5, c4 = idx & 31;
            *(float4*)(eL + row * 132 + c4 * 4) = *(const float4*)(edge + b0 * 128 + idx * 4);
        }
        {
            int h = t >> 5, c4 = t & 31;
            *(float4*)(uL + h * 132 + c4 * 4) = *(const float4*)(u_edge + h * 128 + c4 * 4);
        }
        if (t < 8) cL[t] = c_edge[t];
        __syncthreads();
        const int b2 = t >> 3, h = t & 7;
        float s = 0.f;
        #pragma unroll
        for (int c4 = 0; c4 < 32; ++c4) {
            float4 e = *(const float4*)(eL + b2 * 132 + c4 * 4);
            float4 u = *(const float4*)(uL + h * 132 + c4 * 4);
            s += e.x*u.x + e.y*u.y + e.z*u.z + e.w*u.w;
        }
        score_edge[(b0 + b2) * 8 + h] = s + cL[h];
    }
}

// ---------------------------------------------------------------------------
// Per-atom score tables from hA: s_src_all[n][h], s_dst_all[n][h].
// ---------------------------------------------------------------------------
__global__ __launch_bounds__(256) void sdots_kernel(
    const unsigned short* __restrict__ hA,
    const float* __restrict__ att_src, const float* __restrict__ att_dst,
    float* __restrict__ s_src_all, float* __restrict__ s_dst_all) {
    const int w = threadIdx.x >> 6, l = threadIdx.x & 63;
    const int n = blockIdx.x * 4 + w;
    if (n >= N_ATOMS) return;
    float4 s0 = *(const float4*)(att_src + l * 8);
    float4 s1 = *(const float4*)(att_src + l * 8 + 4);
    float4 d0 = *(const float4*)(att_dst + l * 8);
    float4 d1 = *(const float4*)(att_dst + l * 8 + 4);
    uint4 u = *(const uint4*)(hA + (size_t)n * 512 + l * 8);
    float fa[8];
    fa[0]=bf2f(u.x); fa[1]=bf2f(u.x>>16); fa[2]=bf2f(u.y); fa[3]=bf2f(u.y>>16);
    fa[4]=bf2f(u.z); fa[5]=bf2f(u.z>>16); fa[6]=bf2f(u.w); fa[7]=bf2f(u.w>>16);
    float ps = fa[0]*s0.x + fa[1]*s0.y + fa[2]*s0.z + fa[3]*s0.w
             + fa[4]*s1.x + fa[5]*s1.y + fa[6]*s1.z + fa[7]*s1.w;
    float pd = fa[0]*d0.x + fa[1]*d0.y + fa[2]*d0.z + fa[3]*d0.w
             + fa[4]*d1.x + fa[5]*d1.y + fa[6]*d1.z + fa[7]*d1.w;
    ps += __shfl_xor(ps, 1); ps += __shfl_xor(ps, 2); ps += __shfl_xor(ps, 4);
    pd += __shfl_xor(pd, 1); pd += __shfl_xor(pd, 2); pd += __shfl_xor(pd, 4);
    if ((l & 7) == 0) {
        s_src_all[n * 8 + (l >> 3)] = ps;
        s_dst_all[n * 8 + (l >> 3)] = pd;
    }
}

// ---------------------------------------------------------------------------
// Fused attention v6: TWO ATOMS PER WAVE (n0 = 2*(bid*4+w), n1 = n0+1) ->
// two independent gather streams + two independent two-phase softmax
// pipelines double the memory parallelism per wave. Atom part written as
// bf16 to hOut (proj composes final out, killing its RMW).
// Lane l: head h=l>>3, atom-value channels l*8..+8, z-part (l&7)*16..+16.
// ---------------------------------------------------------------------------
__global__ __launch_bounds__(256, 4) void attn_kernel(
    const unsigned short* __restrict__ hA,
    const float* __restrict__ edge,
    const float* __restrict__ s_src_all,
    const float* __restrict__ s_dst_all,
    const float* __restrict__ score_edge,
    const int* __restrict__ a2a,
    const int* __restrict__ a2b,
    unsigned short* __restrict__ hOut,
    unsigned short* __restrict__ Z) {
    const int w = threadIdx.x >> 6;
    const int l = threadIdx.x & 63;
    const int n0 = (blockIdx.x * 4 + w) * 2;     // grid 2500 -> n0 in [0,19998]
    const int n1 = n0 + 1;
    const int h = l >> 3, sub = l & 7;

    const float ss0 = s_src_all[n0 * 8 + h];
    const float ss1 = s_src_all[n1 * 8 + h];
    const int* pa0 = a2a + n0 * MAX_DEG;
    const int* pb0 = a2b + n0 * MAX_DEG;
    const int* pa1 = a2a + n1 * MAX_DEG;
    const int* pb1 = a2b + n1 * MAX_DEG;

    // ---- phase 1: scores for both atoms (independent gathers) ----
    float pw0[12], pw1[12];
    #pragma unroll
    for (int d = 0; d < 12; ++d) {
        const int ia0 = pa0[d], ib0 = pb0[d];
        const int ia1 = pa1[d], ib1 = pb1[d];
        float s0 = ss0 + s_dst_all[ia0 * 8 + h] + score_edge[ib0 * 8 + h];
        float s1 = ss1 + s_dst_all[ia1 * 8 + h] + score_edge[ib1 * 8 + h];
        s0 = s0 > 0.f ? s0 : 0.2f * s0;
        s1 = s1 > 0.f ? s1 : 0.2f * s1;
        pw0[d] = (ia0 != 0) ? s0 : -3e38f;
        pw1[d] = (ia1 != 0) ? s1 : -3e38f;
    }
    float mx0 = fmaxf(
        fmaxf(fmaxf(fmaxf(pw0[0], pw0[1]), fmaxf(pw0[2], pw0[3])),
              fmaxf(fmaxf(pw0[4], pw0[5]), fmaxf(pw0[6], pw0[7]))),
        fmaxf(fmaxf(pw0[8], pw0[9]), fmaxf(pw0[10], pw0[11])));
    float mx1 = fmaxf(
        fmaxf(fmaxf(fmaxf(pw1[0], pw1[1]), fmaxf(pw1[2], pw1[3])),
              fmaxf(fmaxf(pw1[4], pw1[5]), fmaxf(pw1[6], pw1[7]))),
        fmaxf(fmaxf(pw1[8], pw1[9]), fmaxf(pw1[10], pw1[11])));
    float ls0 = 0.f, ls1 = 0.f;
    #pragma unroll
    for (int d = 0; d < 12; ++d) {
        pw0[d] = __expf(pw0[d] - mx0);  ls0 += pw0[d];
        pw1[d] = __expf(pw1[d] - mx1);  ls1 += pw1[d];
    }
    const float inv0 = ls0 > 0.f ? 1.f / ls0 : 0.f;
    const float inv1 = ls1 > 0.f ? 1.f / ls1 : 0.f;

    // ---- phase 2: independent weighted accumulation, 2 streams ----
    float acc0[8], acc1[8], z0[16], z1[16];
    #pragma unroll
    for (int j = 0; j < 8; ++j) { acc0[j] = 0.f; acc1[j] = 0.f; }
    #pragma unroll
    for (int j = 0; j < 16; ++j) { z0[j] = 0.f; z1[j] = 0.f; }

    #pragma unroll 2
    for (int d = 0; d < 12; ++d) {
        const int ia0 = pa0[d], ib0 = pb0[d];
        const int ia1 = pa1[d], ib1 = pb1[d];
        const float p0 = pw0[d], p1 = pw1[d];
        uint4 ua0 = *(const uint4*)(hA + (size_t)ia0 * 512 + l * 8);
        uint4 ua1 = *(const uint4*)(hA + (size_t)ia1 * 512 + l * 8);
        const float* ep0 = edge + (size_t)ib0 * 128 + sub * 16;
        const float* ep1 = edge + (size_t)ib1 * 128 + sub * 16;
        float4 e00 = *(const float4*)(ep0);
        float4 e01 = *(const float4*)(ep0 + 4);
        float4 e02 = *(const float4*)(ep0 + 8);
        float4 e03 = *(const float4*)(ep0 + 12);
        float4 e10 = *(const float4*)(ep1);
        float4 e11 = *(const float4*)(ep1 + 4);
        float4 e12 = *(const float4*)(ep1 + 8);
        float4 e13 = *(const float4*)(ep1 + 12);

        float fa0[8], fa1[8];
        fa0[0]=bf2f(ua0.x); fa0[1]=bf2f(ua0.x>>16); fa0[2]=bf2f(ua0.y); fa0[3]=bf2f(ua0.y>>16);
        fa0[4]=bf2f(ua0.z); fa0[5]=bf2f(ua0.z>>16); fa0[6]=bf2f(ua0.w); fa0[7]=bf2f(ua0.w>>16);
        fa1[0]=bf2f(ua1.x); fa1[1]=bf2f(ua1.x>>16); fa1[2]=bf2f(ua1.y); fa1[3]=bf2f(ua1.y>>16);
        fa1[4]=bf2f(ua1.z); fa1[5]=bf2f(ua1.z>>16); fa1[6]=bf2f(ua1.w); fa1[7]=bf2f(ua1.w>>16);

        #pragma unroll
        for (int j = 0; j < 8; ++j) { acc0[j] += p0 * fa0[j]; acc1[j] += p1 * fa1[j]; }
        z0[0]+=p0*e00.x; z0[1]+=p0*e00.y; z0[2]+=p0*e00.z; z0[3]+=p0*e00.w;
        z0[4]+=p0*e01.x; z0[5]+=p0*e01.y; z0[6]+=p0*e01.z; z0[7]+=p0*e01.w;
        z0[8]+=p0*e02.x; z0[9]+=p0*e02.y; z0[10]+=p0*e02.z; z0[11]+=p0*e02.w;
        z0[12]+=p0*e03.x; z0[13]+=p0*e03.y; z0[14]+=p0*e03.z; z0[15]+=p0*e03.w;
        z1[0]+=p1*e10.x; z1[1]+=p1*e10.y; z1[2]+=p1*e10.z; z1[3]+=p1*e10.w;
        z1[4]+=p1*e11.x; z1[5]+=p1*e11.y; z1[6]+=p1*e11.z; z1[7]+=p1*e11.w;
        z1[8]+=p1*e12.x; z1[9]+=p1*e12.y; z1[10]+=p1*e12.z; z1[11]+=p1*e12.w;
        z1[12]+=p1*e13.x; z1[13]+=p1*e13.y; z1[14]+=p1*e13.z; z1[15]+=p1*e13.w;
    }

    // ---- write atom parts (bf16) + Z (bf16) ----
    {
        union { unsigned int u[4]; uint4 v; } ap;
        #pragma unroll
        for (int i = 0; i < 4; ++i)
            ap.u[i] = (unsigned int)f2bf(acc0[2*i] * inv0)
                    | ((unsigned int)f2bf(acc0[2*i+1] * inv0) << 16);
        *(uint4*)(hOut + (size_t)n0 * 512 + l * 8) = ap.v;
        #pragma unroll
        for (int i = 0; i < 4; ++i)
            ap.u[i] = (unsigned int)f2bf(acc1[2*i] * inv1)
                    | ((unsigned int)f2bf(acc1[2*i+1] * inv1) << 16);
        *(uint4*)(hOut + (size_t)n1 * 512 + l * 8) = ap.v;
    }
    {
        union { unsigned int u[8]; uint4 v[2]; } zp;
        #pragma unroll
        for (int i = 0; i < 8; ++i)
            zp.u[i] = (unsigned int)f2bf(z0[2*i] * inv0)
                    | ((unsigned int)f2bf(z0[2*i+1] * inv0) << 16);
        unsigned short* zd = Z + (size_t)n0 * 1024 + l * 16;
        *(uint4*)zd = zp.v[0];
        *(uint4*)(zd + 8) = zp.v[1];
        #pragma unroll
        for (int i = 0; i < 8; ++i)
            zp.u[i] = (unsigned int)f2bf(z1[2*i] * inv1)
                    | ((unsigned int)f2bf(z1[2*i+1] * inv1) << 16);
        zd = Z + (size_t)n1 * 1024 + l * 16;
        *(uint4*)zd = zp.v[0];
        *(uint4*)(zd + 8) = zp.v[1];
    }
}

// ---------------------------------------------------------------------------
// Projection pass: out[n][h*64+j] = hOut + (Z[n][h] @ WtB_head) + b_bond.
// No out RMW: single write of the final value.
// ---------------------------------------------------------------------------
__global__ __launch_bounds__(256, 4) void proj_kernel(
    const unsigned short* __restrict__ Z, const unsigned short* __restrict__ WtB,
    const float* __restrict__ b_bond, const unsigned short* __restrict__ hOut,
    float* __restrict__ out) {
    __shared__ unsigned short Bls[64 * 128];      // 16 KB
    const int t = threadIdx.x;
    const int w = t >> 6, l = t & 63;
    const int h = blockIdx.x & 7;                 // head
    const int mt = blockIdx.x >> 3;               // 0..312

    const int m16 = l & 15, g = l >> 4;
    const int arow = mt * 64 + (w << 4) + m16;

    const unsigned short* Zr = Z + (size_t)arow * 1024 + h * 128 + (g << 3);
    uint4 af[4];
    #pragma unroll
    for (int ks = 0; ks < 4; ++ks)
        af[ks] = *(const uint4*)(Zr + (ks << 5));

    {
        #pragma unroll
        for (int i = 0; i < 4; ++i) {
            int s = (w << 8) + (i << 6) + l;      // 0..1023
            int nrow = s >> 4;
            int kc = (s & 15) ^ (nrow & 7);
            const char* src = (const char*)WtB + (size_t)(h * 64 + nrow) * 256 + kc * 16;
            __builtin_amdgcn_global_load_lds(
                (const __attribute__((address_space(1))) void*)src,
                (__attribute__((address_space(3))) void*)((char*)Bls + (((w << 8) + (i << 6)) << 4)),
                16, 0, 0);
        }
    }
    __syncthreads();

    f32x4 acc[4] = {};
    #pragma unroll
    for (int ks = 0; ks < 4; ++ks) {
        short8v a = *(const short8v*)&af[ks];
        #pragma unroll
        for (int nt = 0; nt < 4; ++nt) {
            int nrow = (nt << 4) + m16;
            const short8v b = *(const short8v*)((const char*)Bls +
                ((nrow * 256 + (ks << 6) + (g << 4)) ^ ((nrow & 7) << 4)));
            acc[nt] = __builtin_amdgcn_mfma_f32_16x16x32_bf16(a, b, acc[nt], 0, 0, 0);
        }
    }

    const int rbase = mt * 64 + (w << 4) + (g << 2);
    #pragma unroll
    for (int nt = 0; nt < 4; ++nt) {
        int col = h * 64 + (nt << 4) + m16;
        float bv = b_bond[col];
        #pragma unroll
        for (int r = 0; r < 4; ++r) {
            int grow = rbase + r;
            if (grow < N_ATOMS) {
                float a0 = bf2f(hOut[(size_t)grow * 512 + col]);
                out[(size_t)grow * 512 + col] = a0 + acc[nt][r] + bv;
            }
        }
    }
}

// ---------------------------------------------------------------------------
extern "C" void kernel_launch(void* const* d_in, const int* in_sizes, int n_in,
                              void* d_out, int out_size, void* d_ws, size_t ws_size,
                              hipStream_t stream) {
    const float* x        = (const float*)d_in[0];
    const float* edge     = (const float*)d_in[1];
    const float* W_atom   = (const float*)d_in[2];
    const float* b_atom   = (const float*)d_in[3];
    const float* W_bond   = (const float*)d_in[4];
    const float* b_bond   = (const float*)d_in[5];
    const float* att_src  = (const float*)d_in[6];
    const float* att_dst  = (const float*)d_in[7];
    const float* att_edge = (const float*)d_in[8];
    const int*   a2a      = (const int*)d_in[9];
    const int*   a2b      = (const int*)d_in[10];
    float* out = (float*)d_out;

    char* ws = (char*)d_ws;
    unsigned short* hA   = (unsigned short*)ws;                    // 20,480,000
    unsigned short* Zb   = (unsigned short*)(ws + 20480000);       // 40,960,000
    unsigned short* WtA  = (unsigned short*)(ws + 61440000);       // 262,144
    unsigned short* WtB  = (unsigned short*)(ws + 61702144);       // 131,072
    float* s_src_all     = (float*)(ws + 61833216);                // 640,000
    float* s_dst_all     = (float*)(ws + 62473216);                // 640,000
    float* score_edge    = (float*)(ws + 63113216);                // 6,400,000
    float* u_edge        = (float*)(ws + 69513216);                // 4,096
    float* c_edge        = (float*)(ws + 69517312);                // 64 (pad)
    unsigned short* hOut = (unsigned short*)(ws + 69517376);       // 20,480,000

    prep_kernel<<<772, 256, 0, stream>>>(W_atom, W_bond, att_edge, b_bond,
                                         WtA, WtB, u_edge, c_edge);

    // fused: atom GEMM (2504 blocks) + escore (6250 blocks)
    stage1_kernel<<<8754, 256, 0, stream>>>(x, WtA, b_atom, hA,
                                            edge, u_edge, c_edge, score_edge);

    sdots_kernel<<<5000, 256, 0, stream>>>(hA, att_src, att_dst, s_src_all, s_dst_all);

    // 2 atoms per wave: 2500 blocks x 4 waves x 2 atoms = 20000
    attn_kernel<<<2500, 256, 0, stream>>>(
        hA, edge, s_src_all, s_dst_all, score_edge, a2a, a2b, hOut, Zb);

    proj_kernel<<<313 * 8, 256, 0, stream>>>(Zb, WtB, b_bond, hOut, out);
}

// Round 14
// 148.493 us; speedup vs baseline: 1.6794x; 1.6794x over previous
//
#include <hip/hip_runtime.h>
#include <hip/hip_bf16.h>

#define N_ATOMS 20000
#define N_BONDS 200000
#define MAX_DEG 12
#define IN_DIM 256
#define BOND_DIM 128
#define OUT_DIM 512
#define N_HEADS 8
#define HEAD_DIM 64

typedef __attribute__((ext_vector_type(8))) short short8v;
typedef __attribute__((ext_vector_type(4))) float f32x4;

static __device__ __forceinline__ float bf2f(unsigned int u) {
    union { unsigned int i; float f; } c;
    c.i = (u & 0xffffu) << 16;
    return c.f;
}
static __device__ __forceinline__ unsigned short f2bf(float f) {
    union { float f; unsigned int i; } c;
    c.f = f;
    unsigned int x = c.i;
    x += 0x7fffu + ((x >> 16) & 1u);   // round-to-nearest-even
    return (unsigned short)(x >> 16);
}

// ---------------------------------------------------------------------------
// PREP (fused): WtA (blocks 0..511), WtB (512..767), u_edge/c_edge (768..771)
// ---------------------------------------------------------------------------
__global__ __launch_bounds__(256) void prep_kernel(
    const float* __restrict__ W_atom, const float* __restrict__ W_bond,
    const float* __restrict__ att_edge, const float* __restrict__ b_bond,
    unsigned short* __restrict__ WtA, unsigned short* __restrict__ WtB,
    float* __restrict__ u_edge, float* __restrict__ c_edge) {
    const int b = blockIdx.x;
    if (b < 512) {                      // WtA[n][k] = bf16(W_atom[k][n]), K=256
        int id = b * 256 + threadIdx.x;
        int n = id >> 8, k = id & 255;
        WtA[id] = f2bf(W_atom[(size_t)k * 512 + n]);
    } else if (b < 768) {               // WtB[n][k] = bf16(W_bond[k][n]), K=128
        int id = (b - 512) * 256 + threadIdx.x;
        int n = id >> 7, k = id & 127;
        WtB[id] = f2bf(W_bond[(size_t)k * 512 + n]);
    } else {                            // u_edge / c_edge
        int tid = (b - 768) * 256 + threadIdx.x;
        if (tid >= 1024) return;
        int h = tid >> 7, c = tid & 127;
        const float* wrow = W_bond + (size_t)c * 512 + h * 64;
        const float* ae = att_edge + h * 64;
        float s = 0.f;
        #pragma unroll 8
        for (int k = 0; k < 64; ++k) s += wrow[k] * ae[k];
        u_edge[h * 128 + c] = s;
        if (c == 0) {
            float cs = 0.f;
            const float* bb = b_bond + h * 64;
            for (int k = 0; k < 64; ++k) cs += bb[k] * ae[k];
            c_edge[h] = cs;
        }
    }
}

// ---------------------------------------------------------------------------
// STAGE1 (fused): blocks 0..2503 = atom GEMM (round-4 proven, XCD swizzle);
// blocks 2504..8753 = escore + bf16 edge copy. Union LDS (21152 B).
// ---------------------------------------------------------------------------
__global__ __launch_bounds__(256) void stage1_kernel(
    const float* __restrict__ x, const unsigned short* __restrict__ WtA,
    const float* __restrict__ b_atom, unsigned short* __restrict__ hA,
    const float* __restrict__ edge, const float* __restrict__ u_edge,
    const float* __restrict__ c_edge, float* __restrict__ score_edge,
    unsigned short* __restrict__ edgeB) {
    __shared__ __align__(16) unsigned char smem[21152];
    const int t = threadIdx.x;

    if (blockIdx.x < 2504) {
        // ================= ATOM GEMM path (M=20000, K=256, nbm=313) ========
        unsigned short* Als = (unsigned short*)smem;
        unsigned short* Bls = (unsigned short*)(smem + 8192);
        const int wgid = (blockIdx.x & 7) * 313 + (blockIdx.x >> 3);
        const int bn = wgid & 7;
        const int bm = wgid >> 3;
        const int w = t >> 6;
        const int l = t & 63;

        f32x4 acc[4] = {};

        for (int kk = 0; kk < 4; ++kk) {
            #pragma unroll
            for (int i = 0; i < 2; ++i) {
                int c = t + i * 256;
                int row = c >> 3;
                int k8 = (c & 7) << 3;
                int grow = (bm << 6) + row;
                float f[8];
                if (grow < N_ATOMS) {
                    const float* src = x + (size_t)grow * 256 + (kk << 6) + k8;
                    float4 v0 = *(const float4*)src;
                    float4 v1 = *(const float4*)(src + 4);
                    f[0] = v0.x; f[1] = v0.y; f[2] = v0.z; f[3] = v0.w;
                    f[4] = v1.x; f[5] = v1.y; f[6] = v1.z; f[7] = v1.w;
                } else {
                    #pragma unroll
                    for (int j = 0; j < 8; ++j) f[j] = 0.f;
                }
                union { unsigned short us[8]; uint4 v; } pk;
                #pragma unroll
                for (int j = 0; j < 8; ++j) pk.us[j] = f2bf(f[j]);
                int byte = ((row << 7) + (k8 << 1)) ^ ((row & 7) << 4);
                *(uint4*)((char*)Als + byte) = pk.v;
            }
            #pragma unroll
            for (int i = 0; i < 2; ++i) {
                int c = t + i * 256;
                int row = c >> 3;
                int k8 = (c & 7) << 3;
                int gn = (bn << 6) + row;
                uint4 v = *(const uint4*)(WtA + (size_t)gn * 256 + (kk << 6) + k8);
                int byte = ((row << 7) + (k8 << 1)) ^ ((row & 7) << 4);
                *(uint4*)((char*)Bls + byte) = v;
            }
            __syncthreads();

            const int m = l & 15;
            const int kg = (l >> 4) << 3;
            #pragma unroll
            for (int ks = 0; ks < 2; ++ks) {
                int kcol = (ks << 5) + kg;
                int arow = (w << 4) + m;
                short8v a = *(short8v*)((char*)Als +
                    (((arow << 7) + (kcol << 1)) ^ ((arow & 7) << 4)));
                #pragma unroll
                for (int nt = 0; nt < 4; ++nt) {
                    int nrow = (nt << 4) + m;
                    short8v bfr = *(short8v*)((char*)Bls +
                        (((nrow << 7) + (kcol << 1)) ^ ((nrow & 7) << 4)));
                    acc[nt] = __builtin_amdgcn_mfma_f32_16x16x32_bf16(a, bfr, acc[nt], 0, 0, 0);
                }
            }
            __syncthreads();
        }

        const int m = l & 15;
        const int rbase = (bm << 6) + (w << 4) + ((l >> 4) << 2);
        #pragma unroll
        for (int nt = 0; nt < 4; ++nt) {
            int col = (bn << 6) + (nt << 4) + m;
            float bv = b_atom[col];
            #pragma unroll
            for (int r = 0; r < 4; ++r) {
                int grow = rbase + r;
                if (grow < N_ATOMS) hA[(size_t)grow * 512 + col] = f2bf(acc[nt][r] + bv);
            }
        }
    } else {
        // ========== ESCORE + bf16-edge-copy path: 32 bonds/block ===========
        float* eL = (float*)smem;                 // 32*132 floats
        float* uL = (float*)(smem + 16896);       // 8*132 floats
        float* cL = (float*)(smem + 21120);       // 8 floats
        const size_t b0 = (size_t)(blockIdx.x - 2504) * 32;
        #pragma unroll
        for (int i = 0; i < 4; ++i) {
            int idx = i * 256 + t;
            int row = idx >> 5, c4 = idx & 31;
            *(float4*)(eL + row * 132 + c4 * 4) = *(const float4*)(edge + b0 * 128 + idx * 4);
        }
        {
            int h = t >> 5, c4 = t & 31;
            *(float4*)(uL + h * 132 + c4 * 4) = *(const float4*)(u_edge + h * 128 + c4 * 4);
        }
        if (t < 8) cL[t] = c_edge[t];
        __syncthreads();
        const int b2 = t >> 3, h = t & 7;
        float s = 0.f;
        #pragma unroll
        for (int c4 = 0; c4 < 32; ++c4) {
            float4 e = *(const float4*)(eL + b2 * 132 + c4 * 4);
            float4 u = *(const float4*)(uL + h * 132 + c4 * 4);
            s += e.x*u.x + e.y*u.y + e.z*u.z + e.w*u.w;
        }
        score_edge[(b0 + b2) * 8 + h] = s + cL[h];

        // bf16 edge copy: thread t -> bond row t>>3, chunk (t&7)*16 (16 ch)
        {
            const int row = t >> 3, c0 = (t & 7) * 16;
            const float* src = eL + row * 132 + c0;
            union { unsigned int u[8]; uint4 v[2]; } pk;
            #pragma unroll
            for (int i = 0; i < 8; ++i)
                pk.u[i] = (unsigned int)f2bf(src[2*i])
                        | ((unsigned int)f2bf(src[2*i+1]) << 16);
            unsigned short* dst = edgeB + (b0 + row) * 128 + c0;
            *(uint4*)dst = pk.v[0];
            *(uint4*)(dst + 8) = pk.v[1];
        }
    }
}

// ---------------------------------------------------------------------------
// Per-atom score tables from hA: s_src_all[n][h], s_dst_all[n][h].
// ---------------------------------------------------------------------------
__global__ __launch_bounds__(256) void sdots_kernel(
    const unsigned short* __restrict__ hA,
    const float* __restrict__ att_src, const float* __restrict__ att_dst,
    float* __restrict__ s_src_all, float* __restrict__ s_dst_all) {
    const int w = threadIdx.x >> 6, l = threadIdx.x & 63;
    const int n = blockIdx.x * 4 + w;
    if (n >= N_ATOMS) return;
    float4 s0 = *(const float4*)(att_src + l * 8);
    float4 s1 = *(const float4*)(att_src + l * 8 + 4);
    float4 d0 = *(const float4*)(att_dst + l * 8);
    float4 d1 = *(const float4*)(att_dst + l * 8 + 4);
    uint4 u = *(const uint4*)(hA + (size_t)n * 512 + l * 8);
    float fa[8];
    fa[0]=bf2f(u.x); fa[1]=bf2f(u.x>>16); fa[2]=bf2f(u.y); fa[3]=bf2f(u.y>>16);
    fa[4]=bf2f(u.z); fa[5]=bf2f(u.z>>16); fa[6]=bf2f(u.w); fa[7]=bf2f(u.w>>16);
    float ps = fa[0]*s0.x + fa[1]*s0.y + fa[2]*s0.z + fa[3]*s0.w
             + fa[4]*s1.x + fa[5]*s1.y + fa[6]*s1.z + fa[7]*s1.w;
    float pd = fa[0]*d0.x + fa[1]*d0.y + fa[2]*d0.z + fa[3]*d0.w
             + fa[4]*d1.x + fa[5]*d1.y + fa[6]*d1.z + fa[7]*d1.w;
    ps += __shfl_xor(ps, 1); ps += __shfl_xor(ps, 2); ps += __shfl_xor(ps, 4);
    pd += __shfl_xor(pd, 1); pd += __shfl_xor(pd, 2); pd += __shfl_xor(pd, 4);
    if ((l & 7) == 0) {
        s_src_all[n * 8 + (l >> 3)] = ps;
        s_dst_all[n * 8 + (l >> 3)] = pd;
    }
}

// ---------------------------------------------------------------------------
// Fused attention v7 = r12's proven two-phase structure, with:
//  - phase-2 edge gather from bf16 edgeB (half the bytes)
//  - atom part written bf16 to hOut (proj composes final out)
// Lane l: head h=l>>3, atom-value channels l*8..+8, z-part (l&7)*16..+16.
// ---------------------------------------------------------------------------
__global__ __launch_bounds__(256) void attn_kernel(
    const unsigned short* __restrict__ hA,
    const unsigned short* __restrict__ edgeB,
    const float* __restrict__ s_src_all,
    const float* __restrict__ s_dst_all,
    const float* __restrict__ score_edge,
    const int* __restrict__ a2a,
    const int* __restrict__ a2b,
    unsigned short* __restrict__ hOut,
    unsigned short* __restrict__ Z) {
    const int w = threadIdx.x >> 6;
    const int l = threadIdx.x & 63;
    const int n = blockIdx.x * 4 + w;
    if (n >= N_ATOMS) return;
    const int h = l >> 3, sub = l & 7;

    const float ss = s_src_all[n * 8 + h];
    const int* pa = a2a + n * MAX_DEG;
    const int* pb = a2b + n * MAX_DEG;

    // ---- phase 1: all score gathers independent; exact softmax in regs ----
    float pw[12];
    #pragma unroll
    for (int d = 0; d < 12; ++d) {
        const int iad = pa[d];
        const int ibd = pb[d];
        float sd = s_dst_all[iad * 8 + h];
        float se = score_edge[ibd * 8 + h];
        float s = ss + sd + se;
        s = s > 0.f ? s : 0.2f * s;                 // leaky_relu(0.2)
        pw[d] = (iad != 0) ? s : -3e38f;            // sentinel for masked
    }
    float mx = fmaxf(
        fmaxf(fmaxf(fmaxf(pw[0], pw[1]), fmaxf(pw[2], pw[3])),
              fmaxf(fmaxf(pw[4], pw[5]), fmaxf(pw[6], pw[7]))),
        fmaxf(fmaxf(pw[8], pw[9]), fmaxf(pw[10], pw[11])));
    float lsum = 0.f;
    #pragma unroll
    for (int d = 0; d < 12; ++d) {
        pw[d] = __expf(pw[d] - mx);                 // masked: exp(-huge) = 0
        lsum += pw[d];
    }
    const float inv = lsum > 0.f ? 1.f / lsum : 0.f;

    // ---- phase 2: independent weighted accumulation (no chain) ----
    float acc[8], z[16];
    #pragma unroll
    for (int j = 0; j < 8; ++j) acc[j] = 0.f;
    #pragma unroll
    for (int j = 0; j < 16; ++j) z[j] = 0.f;

    #pragma unroll 2
    for (int d = 0; d < 12; ++d) {
        const int iad = pa[d];
        const int ibd = pb[d];
        const float p = pw[d];
        uint4 ua = *(const uint4*)(hA + (size_t)iad * 512 + l * 8);
        const unsigned short* ep = edgeB + (size_t)ibd * 128 + sub * 16;
        uint4 eb0 = *(const uint4*)(ep);
        uint4 eb1 = *(const uint4*)(ep + 8);

        float fa[8];
        fa[0]=bf2f(ua.x); fa[1]=bf2f(ua.x>>16); fa[2]=bf2f(ua.y); fa[3]=bf2f(ua.y>>16);
        fa[4]=bf2f(ua.z); fa[5]=bf2f(ua.z>>16); fa[6]=bf2f(ua.w); fa[7]=bf2f(ua.w>>16);

        #pragma unroll
        for (int j = 0; j < 8; ++j) acc[j] += p * fa[j];
        z[0]  += p * bf2f(eb0.x);       z[1]  += p * bf2f(eb0.x >> 16);
        z[2]  += p * bf2f(eb0.y);       z[3]  += p * bf2f(eb0.y >> 16);
        z[4]  += p * bf2f(eb0.z);       z[5]  += p * bf2f(eb0.z >> 16);
        z[6]  += p * bf2f(eb0.w);       z[7]  += p * bf2f(eb0.w >> 16);
        z[8]  += p * bf2f(eb1.x);       z[9]  += p * bf2f(eb1.x >> 16);
        z[10] += p * bf2f(eb1.y);       z[11] += p * bf2f(eb1.y >> 16);
        z[12] += p * bf2f(eb1.z);       z[13] += p * bf2f(eb1.z >> 16);
        z[14] += p * bf2f(eb1.w);       z[15] += p * bf2f(eb1.w >> 16);
    }

    // ---- atom part -> hOut (bf16) ----
    {
        union { unsigned int u[4]; uint4 v; } ap;
        #pragma unroll
        for (int i = 0; i < 4; ++i)
            ap.u[i] = (unsigned int)f2bf(acc[2*i] * inv)
                    | ((unsigned int)f2bf(acc[2*i+1] * inv) << 16);
        *(uint4*)(hOut + (size_t)n * 512 + l * 8) = ap.v;
    }

    // Z[n][h*128 + sub*16 .. +16] bf16: lane l -> 32B at l*32, coalesced
    union { unsigned int u[8]; uint4 v[2]; } zp;
    #pragma unroll
    for (int i = 0; i < 8; ++i)
        zp.u[i] = (unsigned int)f2bf(z[2*i] * inv)
                | ((unsigned int)f2bf(z[2*i+1] * inv) << 16);
    unsigned short* zdst = Z + (size_t)n * 1024 + l * 16;
    *(uint4*)zdst = zp.v[0];
    *(uint4*)(zdst + 8) = zp.v[1];
}

// ---------------------------------------------------------------------------
// Projection pass: out[n][h*64+j] = hOut + (Z[n][h] @ WtB_head) + b_bond.
// Single final write of out (no RMW).
// ---------------------------------------------------------------------------
__global__ __launch_bounds__(256, 4) void proj_kernel(
    const unsigned short* __restrict__ Z, const unsigned short* __restrict__ WtB,
    const float* __restrict__ b_bond, const unsigned short* __restrict__ hOut,
    float* __restrict__ out) {
    __shared__ unsigned short Bls[64 * 128];      // 16 KB
    const int t = threadIdx.x;
    const int w = t >> 6, l = t & 63;
    const int h = blockIdx.x & 7;                 // head
    const int mt = blockIdx.x >> 3;               // 0..312

    const int m16 = l & 15, g = l >> 4;
    const int arow = mt * 64 + (w << 4) + m16;

    const unsigned short* Zr = Z + (size_t)arow * 1024 + h * 128 + (g << 3);
    uint4 af[4];
    #pragma unroll
    for (int ks = 0; ks < 4; ++ks)
        af[ks] = *(const uint4*)(Zr + (ks << 5));

    {
        #pragma unroll
        for (int i = 0; i < 4; ++i) {
            int s = (w << 8) + (i << 6) + l;      // 0..1023
            int nrow = s >> 4;
            int kc = (s & 15) ^ (nrow & 7);
            const char* src = (const char*)WtB + (size_t)(h * 64 + nrow) * 256 + kc * 16;
            __builtin_amdgcn_global_load_lds(
                (const __attribute__((address_space(1))) void*)src,
                (__attribute__((address_space(3))) void*)((char*)Bls + (((w << 8) + (i << 6)) << 4)),
                16, 0, 0);
        }
    }
    __syncthreads();

    f32x4 acc[4] = {};
    #pragma unroll
    for (int ks = 0; ks < 4; ++ks) {
        short8v a = *(const short8v*)&af[ks];
        #pragma unroll
        for (int nt = 0; nt < 4; ++nt) {
            int nrow = (nt << 4) + m16;
            const short8v b = *(const short8v*)((const char*)Bls +
                ((nrow * 256 + (ks << 6) + (g << 4)) ^ ((nrow & 7) << 4)));
            acc[nt] = __builtin_amdgcn_mfma_f32_16x16x32_bf16(a, b, acc[nt], 0, 0, 0);
        }
    }

    const int rbase = mt * 64 + (w << 4) + (g << 2);
    #pragma unroll
    for (int nt = 0; nt < 4; ++nt) {
        int col = h * 64 + (nt << 4) + m16;
        float bv = b_bond[col];
        #pragma unroll
        for (int r = 0; r < 4; ++r) {
            int grow = rbase + r;
            if (grow < N_ATOMS) {
                float a0 = bf2f(hOut[(size_t)grow * 512 + col]);
                out[(size_t)grow * 512 + col] = a0 + acc[nt][r] + bv;
            }
        }
    }
}

// ---------------------------------------------------------------------------
extern "C" void kernel_launch(void* const* d_in, const int* in_sizes, int n_in,
                              void* d_out, int out_size, void* d_ws, size_t ws_size,
                              hipStream_t stream) {
    const float* x        = (const float*)d_in[0];
    const float* edge     = (const float*)d_in[1];
    const float* W_atom   = (const float*)d_in[2];
    const float* b_atom   = (const float*)d_in[3];
    const float* W_bond   = (const float*)d_in[4];
    const float* b_bond   = (const float*)d_in[5];
    const float* att_src  = (const float*)d_in[6];
    const float* att_dst  = (const float*)d_in[7];
    const float* att_edge = (const float*)d_in[8];
    const int*   a2a      = (const int*)d_in[9];
    const int*   a2b      = (const int*)d_in[10];
    float* out = (float*)d_out;

    char* ws = (char*)d_ws;
    unsigned short* hA    = (unsigned short*)ws;                    // 20,480,000
    unsigned short* Zb    = (unsigned short*)(ws + 20480000);       // 40,960,000
    unsigned short* WtA   = (unsigned short*)(ws + 61440000);       // 262,144
    unsigned short* WtB   = (unsigned short*)(ws + 61702144);       // 131,072
    float* s_src_all      = (float*)(ws + 61833216);                // 640,000
    float* s_dst_all      = (float*)(ws + 62473216);                // 640,000
    float* score_edge     = (float*)(ws + 63113216);                // 6,400,000
    float* u_edge         = (float*)(ws + 69513216);                // 4,096
    float* c_edge         = (float*)(ws + 69517312);                // 64 (pad)
    unsigned short* hOut  = (unsigned short*)(ws + 69517376);       // 20,480,000
    unsigned short* edgeB = (unsigned short*)(ws + 89997376);       // 51,200,000

    prep_kernel<<<772, 256, 0, stream>>>(W_atom, W_bond, att_edge, b_bond,
                                         WtA, WtB, u_edge, c_edge);

    // fused: atom GEMM (2504 blocks) + escore/edgeB (6250 blocks)
    stage1_kernel<<<8754, 256, 0, stream>>>(x, WtA, b_atom, hA,
                                            edge, u_edge, c_edge, score_edge, edgeB);

    sdots_kernel<<<5000, 256, 0, stream>>>(hA, att_src, att_dst, s_src_all, s_dst_all);

    attn_kernel<<<5000, 256, 0, stream>>>(
        hA, edgeB, s_src_all, s_dst_all, score_edge, a2a, a2b, hOut, Zb);

    proj_kernel<<<313 * 8, 256, 0, stream>>>(Zb, WtB, b_bond, hOut, out);
}